// Round 5
// baseline (102.130 us; speedup 1.0000x reference)
//
#include <hip/hip_runtime.h>
#include <hip/hip_bf16.h>
#include <math.h>

#define FEAT 1024
#define HID  512
#define DK   256
#define NROWS 8192

typedef __attribute__((ext_vector_type(8))) short short8;
typedef __attribute__((ext_vector_type(4))) float floatx4;

// RNE float -> bf16 (raw u16).
__device__ __forceinline__ unsigned short f2bf(float x) {
    union { float f; unsigned u; } u;
    u.f = x;
    unsigned r = u.u;
    r += 0x7fffu + ((r >> 16) & 1u);
    return (unsigned short)(r >> 16);
}
__device__ __forceinline__ float bf2f(unsigned short x) {
    union { unsigned u; float f; } u;
    u.u = ((unsigned)x) << 16;
    return u.f;
}

// Order-preserving float<->uint encoding for atomicMax on floats.
__device__ __forceinline__ unsigned fenc(float f) {
    unsigned b = __float_as_uint(f);
    return (b & 0x80000000u) ? ~b : (b | 0x80000000u);
}
__device__ __forceinline__ float fdec(unsigned u) {
    return __uint_as_float((u & 0x80000000u) ? (u ^ 0x80000000u) : ~u);
}

__device__ __forceinline__ void gld_lds16(const unsigned short* g, unsigned short* l) {
    __builtin_amdgcn_global_load_lds(
        (__attribute__((address_space(1))) void*)(void*)g,
        (__attribute__((address_space(3))) void*)l,
        16, 0, 0);
}

// ---------------------------------------------------------------------------
// prep: one launch does (a) X fp32->bf16 cast, (b) all 4 weight transposes
// (f32 [K][N] -> bf16 [N][K]), (c) zero P/Z/mx accumulators.
// Flat grid: blocks [0,8192) cast; [8192,8704) W1T; [8704,9088) Wq/Wk/WvT.
// ---------------------------------------------------------------------------
__global__ __launch_bounds__(256) void prep_kernel(
    const float* __restrict__ X, const float* __restrict__ W1,
    const float* __restrict__ Wq, const float* __restrict__ Wk,
    const float* __restrict__ Wv,
    unsigned short* __restrict__ Xb, unsigned short* __restrict__ W1T,
    unsigned short* __restrict__ WqT, unsigned short* __restrict__ WkT,
    unsigned short* __restrict__ WvT,
    float* __restrict__ P, float* __restrict__ Z, unsigned* __restrict__ mx_enc)
{
    const int b = blockIdx.x;
    const int tid = threadIdx.x;

    if (b == 0) {
        for (int i = tid; i < 3 * DK; i += 256) P[i] = 0.f;
        if (tid < 3) { Z[tid] = 0.f; mx_enc[tid] = 0u; }
    }
    if (b < 8192) {                 // cast: 8192 blocks x 256 thr x 1 float4
        int i = b * 256 + tid;
        float4 v = ((const float4*)X)[i];
        ushort4 o;
        o.x = f2bf(v.x); o.y = f2bf(v.y); o.z = f2bf(v.z); o.w = f2bf(v.w);
        ((ushort4*)Xb)[i] = o;
        return;
    }
    int t = b - 8192;
    const float* in; unsigned short* outp; int K, N, tn, tk;
    if (t < 512) {                  // W1: 16 n-tiles x 32 k-tiles
        in = W1; outp = W1T; K = FEAT; N = HID; tn = t & 15; tk = t >> 4;
    } else {                        // Wq/Wk/Wv: 8 n-tiles x 16 k-tiles each
        t -= 512;
        int z = t >> 7, r = t & 127;
        K = HID; N = DK; tn = r & 7; tk = r >> 3;
        in   = (z == 0) ? Wq  : (z == 1) ? Wk  : Wv;
        outp = (z == 0) ? WqT : (z == 1) ? WkT : WvT;
    }
    __shared__ float tt[32][33];
    const int tx = tid & 31, ty = tid >> 5;
    const int n0 = tn * 32, k0 = tk * 32;
    #pragma unroll
    for (int i2 = ty; i2 < 32; i2 += 8)
        tt[i2][tx] = in[(size_t)(k0 + i2) * N + (n0 + tx)];
    __syncthreads();
    #pragma unroll
    for (int i2 = ty; i2 < 32; i2 += 8)
        outp[(size_t)(n0 + i2) * K + (k0 + tx)] = f2bf(tt[tx][i2]);
}

// ---------------------------------------------------------------------------
// MFMA bf16 GEMM: C = bf16([relu](A @ B^T + bias)). A [M][K] bf16, BT [N][K].
// 64x128 tile, BK=32, 256 thr = 4 waves (2x2), per-wave 2x4 16x16x32 frags.
// global_load_lds staging with 16B-granule XOR swizzle on the global source;
// same XOR on ds_read addr. blockIdx.z batches up to 3 (BT,bias,C).
// ---------------------------------------------------------------------------
__global__ __launch_bounds__(256) void gemm_mfma(
    const unsigned short* __restrict__ A,
    const unsigned short* __restrict__ BT0, const unsigned short* __restrict__ BT1,
    const unsigned short* __restrict__ BT2,
    const float* __restrict__ bias0, const float* __restrict__ bias1,
    const float* __restrict__ bias2,
    unsigned short* __restrict__ C0, unsigned short* __restrict__ C1,
    unsigned short* __restrict__ C2,
    int N, int K, int relu)
{
    const unsigned short* BT = (blockIdx.z == 0) ? BT0 : (blockIdx.z == 1) ? BT1 : BT2;
    const float* bias        = (blockIdx.z == 0) ? bias0 : (blockIdx.z == 1) ? bias1 : bias2;
    unsigned short* C        = (blockIdx.z == 0) ? C0 : (blockIdx.z == 1) ? C1 : C2;

    __shared__ __align__(16) unsigned short As[64 * 32];    // 4 KB
    __shared__ __align__(16) unsigned short Bs[128 * 32];   // 8 KB

    const int tid  = threadIdx.x;
    const int lane = tid & 63;
    const int wid  = tid >> 6;
    const int wm = wid >> 1, wn = wid & 1;
    const int m0 = blockIdx.y * 64, n0 = blockIdx.x * 128;

    // A staging: 64 rows x 4 granules = 256 granules, 1/thread.
    const int rowA = tid >> 2, gA = tid & 3;
    const int sgA = gA ^ ((rowA >> 1) & 3);
    const unsigned short* Ap = A + (size_t)(m0 + rowA) * K + sgA * 8;

    // B staging: 128 rows x 4 granules = 512 granules, 2/thread.
    const int idx0 = tid, idx1 = tid + 256;
    const int rowB0 = idx0 >> 2, gB0 = idx0 & 3;
    const int rowB1 = idx1 >> 2, gB1 = idx1 & 3;
    const int sgB0 = gB0 ^ ((rowB0 >> 1) & 3);
    const int sgB1 = gB1 ^ ((rowB1 >> 1) & 3);
    const unsigned short* Bp0 = BT + (size_t)(n0 + rowB0) * K + sgB0 * 8;
    const unsigned short* Bp1 = BT + (size_t)(n0 + rowB1) * K + sgB1 * 8;

    char* AsB = (char*)As;
    char* BsB = (char*)Bs;
    const int ldsA  = wid * 1024;          // wave-uniform dest bases
    const int ldsB0 = wid * 1024;
    const int ldsB1 = wid * 1024 + 4096;

    // Fragment ds_read byte offsets (swizzled).
    const int gr = lane >> 4;
    int aoff[2], boff[4];
    #pragma unroll
    for (int i = 0; i < 2; ++i) {
        int ra = wm * 32 + i * 16 + (lane & 15);
        aoff[i] = ra * 64 + ((gr ^ ((ra >> 1) & 3)) * 16);
    }
    #pragma unroll
    for (int j = 0; j < 4; ++j) {
        int rb = wn * 64 + j * 16 + (lane & 15);
        boff[j] = rb * 64 + ((gr ^ ((rb >> 1) & 3)) * 16);
    }

    floatx4 acc[2][4];
    #pragma unroll
    for (int i = 0; i < 2; ++i)
        #pragma unroll
        for (int j = 0; j < 4; ++j)
            acc[i][j] = (floatx4){0.f, 0.f, 0.f, 0.f};

    for (int kt = 0; kt < K; kt += 32) {
        gld_lds16(Ap  + kt, (unsigned short*)(AsB + ldsA));
        gld_lds16(Bp0 + kt, (unsigned short*)(BsB + ldsB0));
        gld_lds16(Bp1 + kt, (unsigned short*)(BsB + ldsB1));
        __syncthreads();   // waits vmcnt(0): LDS tiles resident

        short8 af[2], bfr[4];
        #pragma unroll
        for (int i = 0; i < 2; ++i) af[i] = *(const short8*)(AsB + aoff[i]);
        #pragma unroll
        for (int j = 0; j < 4; ++j) bfr[j] = *(const short8*)(BsB + boff[j]);
        #pragma unroll
        for (int i = 0; i < 2; ++i)
            #pragma unroll
            for (int j = 0; j < 4; ++j)
                acc[i][j] = __builtin_amdgcn_mfma_f32_16x16x32_bf16(
                    af[i], bfr[j], acc[i][j], 0, 0, 0);
        __syncthreads();   // protect LDS before next stage
    }

    // Epilogue: C/D layout col = lane&15, row = (lane>>4)*4 + reg. bf16 out.
    #pragma unroll
    for (int i = 0; i < 2; ++i) {
        int rbase = m0 + wm * 32 + i * 16 + (lane >> 4) * 4;
        #pragma unroll
        for (int j = 0; j < 4; ++j) {
            int c = n0 + wn * 64 + j * 16 + (lane & 15);
            float bb = bias ? bias[c] : 0.f;
            #pragma unroll
            for (int r = 0; r < 4; ++r) {
                float v = acc[i][j][r] + bb;
                if (relu) v = fmaxf(v, 0.f);
                C[(size_t)(rbase + r) * N + c] = f2bf(v);
            }
        }
    }
}

// ---------------------------------------------------------------------------
// Gather + fused max: 128 blocks x 4 waves; each wave handles 16 rows.
// Per row: gather 9 K-rows (bf16), incremental prefix sums in fp32,
// a_raw[sel][i] = q_i . ksum / 16 at prefix lengths {3,5,9}. Block-local max
// per selector -> one encoded atomicMax per (block, sel): 384 atomics total.
// ---------------------------------------------------------------------------
__global__ __launch_bounds__(256) void gather_attn(
    const unsigned short* __restrict__ Q, const unsigned short* __restrict__ Kmat,
    const int* __restrict__ sp, float* __restrict__ a_raw,
    unsigned* __restrict__ mx_enc)
{
    const int lane = threadIdx.x & 63;
    const int wid  = threadIdx.x >> 6;

    float mloc[3] = {-INFINITY, -INFINITY, -INFINITY};

    #pragma unroll 1
    for (int tr = 0; tr < 16; ++tr) {
        const int i = blockIdx.x * 64 + wid * 16 + tr;
        ushort4 qr = *(const ushort4*)(Q + (size_t)i * DK + lane * 4);
        float4 q = make_float4(bf2f(qr.x), bf2f(qr.y), bf2f(qr.z), bf2f(qr.w));
        float4 ks = make_float4(0.f, 0.f, 0.f, 0.f);

        int sel = 0;
        #pragma unroll
        for (int j = 0; j <= 8; ++j) {
            int r = sp[i * 9 + j];
            ushort4 kr = *(const ushort4*)(Kmat + (size_t)r * DK + lane * 4);
            ks.x += bf2f(kr.x); ks.y += bf2f(kr.y);
            ks.z += bf2f(kr.z); ks.w += bf2f(kr.w);
            if (j == 2 || j == 4 || j == 8) {
                float d = q.x * ks.x + q.y * ks.y + q.z * ks.z + q.w * ks.w;
                #pragma unroll
                for (int off = 32; off; off >>= 1) d += __shfl_xor(d, off);
                d *= 0.0625f;                       // /sqrt(256)
                if (lane == 0) a_raw[sel * NROWS + i] = d;
                mloc[sel] = fmaxf(mloc[sel], d);    // all lanes hold same d
                ++sel;
            }
        }
    }

    __shared__ float sm[3][4];
    if (lane == 0) {
        sm[0][wid] = mloc[0]; sm[1][wid] = mloc[1]; sm[2][wid] = mloc[2];
    }
    __syncthreads();
    if (threadIdx.x < 3) {
        float m = fmaxf(fmaxf(sm[threadIdx.x][0], sm[threadIdx.x][1]),
                        fmaxf(sm[threadIdx.x][2], sm[threadIdx.x][3]));
        atomicMax(&mx_enc[threadIdx.x], fenc(m));
    }
}

// ---------------------------------------------------------------------------
// Pools, all 3 selectors in one V pass. Block = 64 rows x 256 cols.
// P[sel][d] += sum_r e[sel][r] * V[r][d]; Z[sel] += sum_r e[sel][r].
// ---------------------------------------------------------------------------
#define RPB 64
__global__ __launch_bounds__(256) void pool_kernel(
    const float* __restrict__ a_raw, const unsigned* __restrict__ mx_enc,
    const unsigned short* __restrict__ V, float* __restrict__ P,
    float* __restrict__ Z)
{
    const int r0 = blockIdx.x * RPB;
    const int t = threadIdx.x;

    __shared__ float e[3][RPB];
    const float m0 = fdec(mx_enc[0]), m1 = fdec(mx_enc[1]), m2 = fdec(mx_enc[2]);

    float z0 = 0.f, z1 = 0.f, z2 = 0.f;
    if (t < RPB) {
        z0 = expf(a_raw[0 * NROWS + r0 + t] - m0);
        z1 = expf(a_raw[1 * NROWS + r0 + t] - m1);
        z2 = expf(a_raw[2 * NROWS + r0 + t] - m2);
        e[0][t] = z0; e[1][t] = z1; e[2][t] = z2;
    }
    __syncthreads();

    float a0 = 0.f, a1 = 0.f, a2 = 0.f;
    for (int r = 0; r < RPB; ++r) {
        float v = bf2f(V[(size_t)(r0 + r) * DK + t]);
        a0 = fmaf(e[0][r], v, a0);
        a1 = fmaf(e[1][r], v, a1);
        a2 = fmaf(e[2][r], v, a2);
    }
    atomicAdd(&P[0 * DK + t], a0);
    atomicAdd(&P[1 * DK + t], a1);
    atomicAdd(&P[2 * DK + t], a2);

    #pragma unroll
    for (int off = 32; off; off >>= 1) {
        z0 += __shfl_xor(z0, off); z1 += __shfl_xor(z1, off); z2 += __shfl_xor(z2, off);
    }
    if (t < RPB && (t & 63) == 0) {
        atomicAdd(&Z[0], z0); atomicAdd(&Z[1], z1); atomicAdd(&Z[2], z2);
    }
}

__global__ __launch_bounds__(256) void final_kernel(
    const float* __restrict__ P, const float* __restrict__ Z,
    const float* __restrict__ Wout, const float* __restrict__ bout,
    float* __restrict__ out)
{
    const int t = threadIdx.x;  // = d in 0..255
    float s = P[t] / Z[0] + P[DK + t] / Z[1] + P[2 * DK + t] / Z[2];
    __shared__ float s0[256], s1[256];
    s0[t] = s * Wout[t * 2 + 0];
    s1[t] = s * Wout[t * 2 + 1];
    __syncthreads();
    for (int st = 128; st; st >>= 1) {
        if (t < st) { s0[t] += s0[t + st]; s1[t] += s1[t + st]; }
        __syncthreads();
    }
    if (t == 0) {
        float a = s0[0] + bout[0], b = s1[0] + bout[1];
        float mm = fmaxf(a, b);
        float ea = expf(a - mm), eb = expf(b - mm);
        float inv = 1.f / (ea + eb);
        out[0] = ea * inv;
        out[1] = eb * inv;
    }
}

// ---------------------------------------------------------------------------
extern "C" void kernel_launch(void* const* d_in, const int* in_sizes, int n_in,
                              void* d_out, int out_size, void* d_ws, size_t ws_size,
                              hipStream_t stream)
{
    const float* X    = (const float*)d_in[0];   // 8192 x 1024
    const int*   sp   = (const int*)  d_in[1];   // 8192 x 9
    const float* W1   = (const float*)d_in[2];   // 1024 x 512
    const float* b1   = (const float*)d_in[3];   // 512
    const float* Wq   = (const float*)d_in[4];   // 512 x 256
    const float* Wk   = (const float*)d_in[5];
    const float* Wv   = (const float*)d_in[6];
    const float* bv   = (const float*)d_in[7];   // 256
    const float* Wout = (const float*)d_in[8];   // 256 x 2
    const float* bout = (const float*)d_in[9];   // 2
    float* out = (float*)d_out;

    // Workspace layout (bytes). Xb (16.8 MB) overlaps Qb/Kb/Vb region —
    // Xb is dead before GEMM2 writes them.
    char* w = (char*)d_ws;
    unsigned short* dense_b = (unsigned short*)(w);             // 8192x512 bf16
    unsigned short* W1T     = (unsigned short*)(w +  8388608);  // 512x1024 bf16
    unsigned short* WqT     = (unsigned short*)(w +  9437184);  // 256x512 bf16
    unsigned short* WkT     = (unsigned short*)(w +  9699328);
    unsigned short* WvT     = (unsigned short*)(w +  9961472);
    float* a_raw            = (float*)(w + 10223616);           // 3*8192 f32
    float* P                = (float*)(w + 10321920);           // 3*256 f32
    float* Z                = P + 3 * DK;                       // 3
    unsigned* mx_enc        = (unsigned*)(Z + 3);               // 3
    unsigned short* Qb      = (unsigned short*)(w + 10485760);  // 8192x256 bf16
    unsigned short* Kb      = (unsigned short*)(w + 14680064);
    unsigned short* Vb      = (unsigned short*)(w + 18874368);
    unsigned short* Xb      = (unsigned short*)(w + 10485760);  // 8192x1024 bf16

    // 0) prep: cast X, transpose all weights, zero accumulators (1 launch)
    prep_kernel<<<8192 + 512 + 384, 256, 0, stream>>>(
        X, W1, Wq, Wk, Wv, Xb, W1T, WqT, WkT, WvT, P, Z, mx_enc);

    // 1) dense_b = bf16(relu(X @ W1 + b1))   [M=8192, N=512, K=1024]
    gemm_mfma<<<dim3(HID / 128, NROWS / 64, 1), 256, 0, stream>>>(
        Xb, W1T, nullptr, nullptr, b1, nullptr, nullptr,
        dense_b, nullptr, nullptr, HID, FEAT, 1);

    // 2) Q/K/V = bf16(dense @ {Wq,Wk,Wv} (+bv on V))  [M=8192, N=256, K=512]
    gemm_mfma<<<dim3(DK / 128, NROWS / 64, 3), 256, 0, stream>>>(
        dense_b, WqT, WkT, WvT, nullptr, nullptr, bv,
        Qb, Kb, Vb, DK, HID, 0);

    // 3) a_raw + per-selector max (fused atomics)
    gather_attn<<<NROWS / 64, 256, 0, stream>>>(Qb, Kb, sp, a_raw, mx_enc);
    // 4) pooled weighted sums (one V pass, all selectors)
    pool_kernel<<<NROWS / RPB, 256, 0, stream>>>(a_raw, mx_enc, Vb, P, Z);
    // 5) epilogue
    final_kernel<<<1, 256, 0, stream>>>(P, Z, Wout, bout, out);
}

// Round 6
// 71.542 us; speedup vs baseline: 1.4276x; 1.4276x over previous
//
#include <hip/hip_runtime.h>
#include <hip/hip_bf16.h>
#include <math.h>

#define FEAT 1024
#define HID  512
#define DK   256
#define NROWS 8192

typedef __attribute__((ext_vector_type(8))) short short8;
typedef __attribute__((ext_vector_type(4))) float floatx4;

// RNE float -> bf16 (raw u16).
__device__ __forceinline__ unsigned short f2bf(float x) {
    union { float f; unsigned u; } u;
    u.f = x;
    unsigned r = u.u;
    r += 0x7fffu + ((r >> 16) & 1u);
    return (unsigned short)(r >> 16);
}
__device__ __forceinline__ float bf2f(unsigned short x) {
    union { unsigned u; float f; } u;
    u.u = ((unsigned)x) << 16;
    return u.f;
}

__device__ __forceinline__ void gld_lds16(const unsigned short* g, unsigned short* l) {
    __builtin_amdgcn_global_load_lds(
        (__attribute__((address_space(1))) void*)(void*)g,
        (__attribute__((address_space(3))) void*)l,
        16, 0, 0);
}

// ---------------------------------------------------------------------------
// prep: one launch does (a) X fp32->bf16 cast, (b) all 4 weight transposes
// (f32 [K][N] -> bf16 [N][K]), (c) zero P/Z accumulators.
// Flat grid: blocks [0,8192) cast; [8192,8704) W1T; [8704,9088) Wq/Wk/WvT.
// ---------------------------------------------------------------------------
__global__ __launch_bounds__(256) void prep_kernel(
    const float* __restrict__ X, const float* __restrict__ W1,
    const float* __restrict__ Wq, const float* __restrict__ Wk,
    const float* __restrict__ Wv,
    unsigned short* __restrict__ Xb, unsigned short* __restrict__ W1T,
    unsigned short* __restrict__ WqT, unsigned short* __restrict__ WkT,
    unsigned short* __restrict__ WvT,
    float* __restrict__ P, float* __restrict__ Z)
{
    const int b = blockIdx.x;
    const int tid = threadIdx.x;

    if (b == 0) {
        for (int i = tid; i < 3 * DK; i += 256) P[i] = 0.f;
        if (tid < 3) Z[tid] = 0.f;
    }
    if (b < 8192) {                 // cast: 8192 blocks x 256 thr x 1 float4
        int i = b * 256 + tid;
        float4 v = ((const float4*)X)[i];
        ushort4 o;
        o.x = f2bf(v.x); o.y = f2bf(v.y); o.z = f2bf(v.z); o.w = f2bf(v.w);
        ((ushort4*)Xb)[i] = o;
        return;
    }
    int t = b - 8192;
    const float* in; unsigned short* outp; int K, N, tn, tk;
    if (t < 512) {                  // W1: 16 n-tiles x 32 k-tiles
        in = W1; outp = W1T; K = FEAT; N = HID; tn = t & 15; tk = t >> 4;
    } else {                        // Wq/Wk/Wv: 8 n-tiles x 16 k-tiles each
        t -= 512;
        int z = t >> 7, r = t & 127;
        K = HID; N = DK; tn = r & 7; tk = r >> 3;
        in   = (z == 0) ? Wq  : (z == 1) ? Wk  : Wv;
        outp = (z == 0) ? WqT : (z == 1) ? WkT : WvT;
    }
    __shared__ float tt[32][33];
    const int tx = tid & 31, ty = tid >> 5;
    const int n0 = tn * 32, k0 = tk * 32;
    #pragma unroll
    for (int i2 = ty; i2 < 32; i2 += 8)
        tt[i2][tx] = in[(size_t)(k0 + i2) * N + (n0 + tx)];
    __syncthreads();
    #pragma unroll
    for (int i2 = ty; i2 < 32; i2 += 8)
        outp[(size_t)(n0 + i2) * K + (k0 + tx)] = f2bf(tt[tx][i2]);
}

// ---------------------------------------------------------------------------
// MFMA bf16 GEMM: C = bf16([relu](A @ B^T + bias)). A [M][K] bf16, BT [N][K].
// 64x128 tile, BK=32, 256 thr = 4 waves (2x2), per-wave 2x4 16x16x32 frags.
// global_load_lds staging with 16B-granule XOR swizzle on the global source;
// same XOR on ds_read addr. blockIdx.z batches up to 3 (BT,bias,C).
// ---------------------------------------------------------------------------
__global__ __launch_bounds__(256) void gemm_mfma(
    const unsigned short* __restrict__ A,
    const unsigned short* __restrict__ BT0, const unsigned short* __restrict__ BT1,
    const unsigned short* __restrict__ BT2,
    const float* __restrict__ bias0, const float* __restrict__ bias1,
    const float* __restrict__ bias2,
    unsigned short* __restrict__ C0, unsigned short* __restrict__ C1,
    unsigned short* __restrict__ C2,
    int N, int K, int relu)
{
    const unsigned short* BT = (blockIdx.z == 0) ? BT0 : (blockIdx.z == 1) ? BT1 : BT2;
    const float* bias        = (blockIdx.z == 0) ? bias0 : (blockIdx.z == 1) ? bias1 : bias2;
    unsigned short* C        = (blockIdx.z == 0) ? C0 : (blockIdx.z == 1) ? C1 : C2;

    __shared__ __align__(16) unsigned short As[64 * 32];    // 4 KB
    __shared__ __align__(16) unsigned short Bs[128 * 32];   // 8 KB

    const int tid  = threadIdx.x;
    const int lane = tid & 63;
    const int wid  = tid >> 6;
    const int wm = wid >> 1, wn = wid & 1;
    const int m0 = blockIdx.y * 64, n0 = blockIdx.x * 128;

    // A staging: 64 rows x 4 granules = 256 granules, 1/thread.
    const int rowA = tid >> 2, gA = tid & 3;
    const int sgA = gA ^ ((rowA >> 1) & 3);
    const unsigned short* Ap = A + (size_t)(m0 + rowA) * K + sgA * 8;

    // B staging: 128 rows x 4 granules = 512 granules, 2/thread.
    const int idx0 = tid, idx1 = tid + 256;
    const int rowB0 = idx0 >> 2, gB0 = idx0 & 3;
    const int rowB1 = idx1 >> 2, gB1 = idx1 & 3;
    const int sgB0 = gB0 ^ ((rowB0 >> 1) & 3);
    const int sgB1 = gB1 ^ ((rowB1 >> 1) & 3);
    const unsigned short* Bp0 = BT + (size_t)(n0 + rowB0) * K + sgB0 * 8;
    const unsigned short* Bp1 = BT + (size_t)(n0 + rowB1) * K + sgB1 * 8;

    char* AsB = (char*)As;
    char* BsB = (char*)Bs;
    const int ldsA  = wid * 1024;          // wave-uniform dest bases
    const int ldsB0 = wid * 1024;
    const int ldsB1 = wid * 1024 + 4096;

    // Fragment ds_read byte offsets (swizzled).
    const int gr = lane >> 4;
    int aoff[2], boff[4];
    #pragma unroll
    for (int i = 0; i < 2; ++i) {
        int ra = wm * 32 + i * 16 + (lane & 15);
        aoff[i] = ra * 64 + ((gr ^ ((ra >> 1) & 3)) * 16);
    }
    #pragma unroll
    for (int j = 0; j < 4; ++j) {
        int rb = wn * 64 + j * 16 + (lane & 15);
        boff[j] = rb * 64 + ((gr ^ ((rb >> 1) & 3)) * 16);
    }

    floatx4 acc[2][4];
    #pragma unroll
    for (int i = 0; i < 2; ++i)
        #pragma unroll
        for (int j = 0; j < 4; ++j)
            acc[i][j] = (floatx4){0.f, 0.f, 0.f, 0.f};

    for (int kt = 0; kt < K; kt += 32) {
        gld_lds16(Ap  + kt, (unsigned short*)(AsB + ldsA));
        gld_lds16(Bp0 + kt, (unsigned short*)(BsB + ldsB0));
        gld_lds16(Bp1 + kt, (unsigned short*)(BsB + ldsB1));
        __syncthreads();   // waits vmcnt(0): LDS tiles resident

        short8 af[2], bfr[4];
        #pragma unroll
        for (int i = 0; i < 2; ++i) af[i] = *(const short8*)(AsB + aoff[i]);
        #pragma unroll
        for (int j = 0; j < 4; ++j) bfr[j] = *(const short8*)(BsB + boff[j]);
        #pragma unroll
        for (int i = 0; i < 2; ++i)
            #pragma unroll
            for (int j = 0; j < 4; ++j)
                acc[i][j] = __builtin_amdgcn_mfma_f32_16x16x32_bf16(
                    af[i], bfr[j], acc[i][j], 0, 0, 0);
        __syncthreads();   // protect LDS before next stage
    }

    // Epilogue: C/D layout col = lane&15, row = (lane>>4)*4 + reg. bf16 out.
    #pragma unroll
    for (int i = 0; i < 2; ++i) {
        int rbase = m0 + wm * 32 + i * 16 + (lane >> 4) * 4;
        #pragma unroll
        for (int j = 0; j < 4; ++j) {
            int c = n0 + wn * 64 + j * 16 + (lane & 15);
            float bb = bias ? bias[c] : 0.f;
            #pragma unroll
            for (int r = 0; r < 4; ++r) {
                float v = acc[i][j][r] + bb;
                if (relu) v = fmaxf(v, 0.f);
                C[(size_t)(rbase + r) * N + c] = f2bf(v);
            }
        }
    }
}

// ---------------------------------------------------------------------------
// Gather: 2048 blocks x 4 waves, ONE ROW PER WAVE (full TLP — the scattered
// K-row reads are latency-bound and need all 8192 waves in flight).
// Per row: gather 9 K-rows (bf16), incremental prefix sums in fp32,
// a_raw[sel][i] = q_i . ksum / 16 at prefix lengths {3,5,9}.
// Per-block 3-selector max -> plain store to mxp[sel][block] (no atomics).
// ---------------------------------------------------------------------------
__global__ __launch_bounds__(256) void gather_attn(
    const unsigned short* __restrict__ Q, const unsigned short* __restrict__ Kmat,
    const int* __restrict__ sp, float* __restrict__ a_raw,
    float* __restrict__ mxp)
{
    const int lane = threadIdx.x & 63;
    const int wid  = threadIdx.x >> 6;
    const int i = blockIdx.x * 4 + wid;

    ushort4 qr = *(const ushort4*)(Q + (size_t)i * DK + lane * 4);
    float4 q = make_float4(bf2f(qr.x), bf2f(qr.y), bf2f(qr.z), bf2f(qr.w));
    float4 ks = make_float4(0.f, 0.f, 0.f, 0.f);

    float mloc[3];
    int sel = 0;
    #pragma unroll
    for (int j = 0; j <= 8; ++j) {
        int r = sp[i * 9 + j];
        ushort4 kr = *(const ushort4*)(Kmat + (size_t)r * DK + lane * 4);
        ks.x += bf2f(kr.x); ks.y += bf2f(kr.y);
        ks.z += bf2f(kr.z); ks.w += bf2f(kr.w);
        if (j == 2 || j == 4 || j == 8) {
            float d = q.x * ks.x + q.y * ks.y + q.z * ks.z + q.w * ks.w;
            #pragma unroll
            for (int off = 32; off; off >>= 1) d += __shfl_xor(d, off);
            d *= 0.0625f;                       // /sqrt(256)
            if (lane == 0) a_raw[sel * NROWS + i] = d;
            mloc[sel] = d;                      // all lanes hold same d
            ++sel;
        }
    }

    __shared__ float sm[3][4];
    if (lane == 0) {
        sm[0][wid] = mloc[0]; sm[1][wid] = mloc[1]; sm[2][wid] = mloc[2];
    }
    __syncthreads();
    if (threadIdx.x < 3) {
        float m = fmaxf(fmaxf(sm[threadIdx.x][0], sm[threadIdx.x][1]),
                        fmaxf(sm[threadIdx.x][2], sm[threadIdx.x][3]));
        mxp[threadIdx.x * 2048 + blockIdx.x] = m;
    }
}

// ---------------------------------------------------------------------------
// Pools, all 3 selectors in one V pass. Block = 64 rows x 256 cols.
// Each block first (redundantly) reduces mxp[3][2048] -> m0..m2 (L2-resident,
// ~cheap) — saves a separate reduce launch + stall.
// P[sel][d] += sum_r e[sel][r] * V[r][d]; Z[sel] += sum_r e[sel][r].
// ---------------------------------------------------------------------------
#define RPB 64
__global__ __launch_bounds__(256) void pool_kernel(
    const float* __restrict__ a_raw, const float* __restrict__ mxp,
    const unsigned short* __restrict__ V, float* __restrict__ P,
    float* __restrict__ Z)
{
    const int r0 = blockIdx.x * RPB;
    const int t = threadIdx.x;

    __shared__ float red[3][256];
    __shared__ float e[3][RPB];

    float m0 = -INFINITY, m1 = -INFINITY, m2 = -INFINITY;
    #pragma unroll
    for (int k = 0; k < 8; ++k) {
        int idx = t + k * 256;
        m0 = fmaxf(m0, mxp[idx]);
        m1 = fmaxf(m1, mxp[2048 + idx]);
        m2 = fmaxf(m2, mxp[4096 + idx]);
    }
    red[0][t] = m0; red[1][t] = m1; red[2][t] = m2;
    __syncthreads();
    for (int st = 128; st; st >>= 1) {
        if (t < st) {
            red[0][t] = fmaxf(red[0][t], red[0][t + st]);
            red[1][t] = fmaxf(red[1][t], red[1][t + st]);
            red[2][t] = fmaxf(red[2][t], red[2][t + st]);
        }
        __syncthreads();
    }
    m0 = red[0][0]; m1 = red[1][0]; m2 = red[2][0];

    float z0 = 0.f, z1 = 0.f, z2 = 0.f;
    if (t < RPB) {
        z0 = expf(a_raw[0 * NROWS + r0 + t] - m0);
        z1 = expf(a_raw[1 * NROWS + r0 + t] - m1);
        z2 = expf(a_raw[2 * NROWS + r0 + t] - m2);
        e[0][t] = z0; e[1][t] = z1; e[2][t] = z2;
    }
    __syncthreads();

    float a0 = 0.f, a1 = 0.f, a2 = 0.f;
    for (int r = 0; r < RPB; ++r) {
        float v = bf2f(V[(size_t)(r0 + r) * DK + t]);
        a0 = fmaf(e[0][r], v, a0);
        a1 = fmaf(e[1][r], v, a1);
        a2 = fmaf(e[2][r], v, a2);
    }
    atomicAdd(&P[0 * DK + t], a0);
    atomicAdd(&P[1 * DK + t], a1);
    atomicAdd(&P[2 * DK + t], a2);

    #pragma unroll
    for (int off = 32; off; off >>= 1) {
        z0 += __shfl_xor(z0, off); z1 += __shfl_xor(z1, off); z2 += __shfl_xor(z2, off);
    }
    if (t == 0) {
        atomicAdd(&Z[0], z0); atomicAdd(&Z[1], z1); atomicAdd(&Z[2], z2);
    }
}

__global__ __launch_bounds__(256) void final_kernel(
    const float* __restrict__ P, const float* __restrict__ Z,
    const float* __restrict__ Wout, const float* __restrict__ bout,
    float* __restrict__ out)
{
    const int t = threadIdx.x;  // = d in 0..255
    float s = P[t] / Z[0] + P[DK + t] / Z[1] + P[2 * DK + t] / Z[2];
    __shared__ float s0[256], s1[256];
    s0[t] = s * Wout[t * 2 + 0];
    s1[t] = s * Wout[t * 2 + 1];
    __syncthreads();
    for (int st = 128; st; st >>= 1) {
        if (t < st) { s0[t] += s0[t + st]; s1[t] += s1[t + st]; }
        __syncthreads();
    }
    if (t == 0) {
        float a = s0[0] + bout[0], b = s1[0] + bout[1];
        float mm = fmaxf(a, b);
        float ea = expf(a - mm), eb = expf(b - mm);
        float inv = 1.f / (ea + eb);
        out[0] = ea * inv;
        out[1] = eb * inv;
    }
}

// ---------------------------------------------------------------------------
extern "C" void kernel_launch(void* const* d_in, const int* in_sizes, int n_in,
                              void* d_out, int out_size, void* d_ws, size_t ws_size,
                              hipStream_t stream)
{
    const float* X    = (const float*)d_in[0];   // 8192 x 1024
    const int*   sp   = (const int*)  d_in[1];   // 8192 x 9
    const float* W1   = (const float*)d_in[2];   // 1024 x 512
    const float* b1   = (const float*)d_in[3];   // 512
    const float* Wq   = (const float*)d_in[4];   // 512 x 256
    const float* Wk   = (const float*)d_in[5];
    const float* Wv   = (const float*)d_in[6];
    const float* bv   = (const float*)d_in[7];   // 256
    const float* Wout = (const float*)d_in[8];   // 256 x 2
    const float* bout = (const float*)d_in[9];   // 2
    float* out = (float*)d_out;

    // Workspace layout (bytes). Xb (16.8 MB) overlaps Qb/Kb/Vb region —
    // Xb is dead before GEMM2 writes them.
    char* w = (char*)d_ws;
    unsigned short* dense_b = (unsigned short*)(w);             // 8192x512 bf16
    unsigned short* W1T     = (unsigned short*)(w +  8388608);  // 512x1024 bf16
    unsigned short* WqT     = (unsigned short*)(w +  9437184);  // 256x512 bf16
    unsigned short* WkT     = (unsigned short*)(w +  9699328);
    unsigned short* WvT     = (unsigned short*)(w +  9961472);
    float* a_raw            = (float*)(w + 10223616);           // 3*8192 f32
    float* P                = (float*)(w + 10321920);           // 3*256 f32
    float* Z                = P + 3 * DK;                       // 3
    float* mxp              = (float*)(w + 10330112);           // 3*2048 f32
    unsigned short* Qb      = (unsigned short*)(w + 10485760);  // 8192x256 bf16
    unsigned short* Kb      = (unsigned short*)(w + 14680064);
    unsigned short* Vb      = (unsigned short*)(w + 18874368);
    unsigned short* Xb      = (unsigned short*)(w + 10485760);  // 8192x1024 bf16

    // 0) prep: cast X, transpose all weights, zero accumulators (1 launch)
    prep_kernel<<<8192 + 512 + 384, 256, 0, stream>>>(
        X, W1, Wq, Wk, Wv, Xb, W1T, WqT, WkT, WvT, P, Z);

    // 1) dense_b = bf16(relu(X @ W1 + b1))   [M=8192, N=512, K=1024]
    gemm_mfma<<<dim3(HID / 128, NROWS / 64, 1), 256, 0, stream>>>(
        Xb, W1T, nullptr, nullptr, b1, nullptr, nullptr,
        dense_b, nullptr, nullptr, HID, FEAT, 1);

    // 2) Q/K/V = bf16(dense @ {Wq,Wk,Wv} (+bv on V))  [M=8192, N=256, K=512]
    gemm_mfma<<<dim3(DK / 128, NROWS / 64, 3), 256, 0, stream>>>(
        dense_b, WqT, WkT, WvT, nullptr, nullptr, bv,
        Qb, Kb, Vb, DK, HID, 0);

    // 3) a_raw + per-block partial maxes (one wave per row, full TLP)
    gather_attn<<<NROWS / 4, 256, 0, stream>>>(Qb, Kb, sp, a_raw, mxp);
    // 4) pooled weighted sums (one V pass, all selectors; folds max-reduce)
    pool_kernel<<<NROWS / RPB, 256, 0, stream>>>(a_raw, mxp, Vb, P, Z);
    // 5) epilogue
    final_kernel<<<1, 256, 0, stream>>>(P, Z, Wout, bout, out);
}